// Round 4
// baseline (3698.811 us; speedup 1.0000x reference)
//
#include <hip/hip_runtime.h>

#define LSEQ 2048
#define TAGS 12

typedef _Float16 half2v __attribute__((ext_vector_type(2)));
typedef unsigned long long u64;

__device__ __forceinline__ float sigm(float x){ return 1.0f/(1.0f+__expf(-x)); }
__device__ __forceinline__ float tanh_fast(float x){ return 1.0f - 2.0f/(1.0f+__expf(2.0f*x)); }
__device__ __forceinline__ half2v pack2(float a, float b){
  half2v r; r.x=(_Float16)a; r.y=(_Float16)b; return r;
}

// Raw workgroup barrier: orders LDS only (lgkmcnt), does NOT drain vmcnt.
__device__ __forceinline__ void wg_barrier(){
  asm volatile("s_waitcnt lgkmcnt(0)" ::: "memory");
  __builtin_amdgcn_s_barrier();
  __builtin_amdgcn_sched_barrier(0);
  asm volatile("" ::: "memory");
}

// XCD-scope exchange primitives. Atomics bypass L1 by architecture and
// execute at the L2 coherence point; WITHOUT sc1 that point is the issuing
// CU's own XCD L2 (same-XCD peers see it in ~200-300 cy), WITH sc1 it is
// the MALL (~2000 cy round trip -- what HIP device-scope atomics emit).
// Round-3's sc0 plain-load fast path demoted everywhere: suspect vector
// sc0 loads don't reliably bypass L1 on gfx950. Atomics remove that mode.
__device__ __forceinline__ void pub_fast(u64* p, u64 v){   // no return, XCD L2
  asm volatile("global_atomic_swap_x2 %0, %1, off"
               :: "v"(p), "v"(v) : "memory");
}
__device__ __forceinline__ u64 poll_fast(u64* p){          // returning, XCD L2
  u64 r, z = 0ull;
  asm volatile("global_atomic_add_x2 %0, %1, %2, off sc0\n\t"
               "s_waitcnt vmcnt(0)"
               : "=&v"(r) : "v"(p), "v"(z) : "memory");
  return r;
}

// K0: zero both exchange buffers (tag 0 never matches step tags in [1,2047]).
__global__ void init_kernel(u64* ex)
{
  int tid = blockIdx.x*256 + threadIdx.x;
  if (tid < 1024) ex[tid] = 0ull;
}

// K1: xg[d][t][row] = b_ih[row]+b_hh[row] + sum_e embed[sent[t]][e] * w_ih[row][e]
__global__ void xg_kernel(
    const int* sent, const float* embed,
    const float* w_ih_f, const float* b_ih_f, const float* b_hh_f,
    const float* w_ih_b, const float* b_ih_b, const float* b_hh_b,
    float* xg)
{
  __shared__ float x_sh[8][256];
  int tid = threadIdx.x;
  int t0 = blockIdx.x * 8;
  for (int i=0;i<8;++i){
    int idx = sent[t0+i];
    x_sh[i][tid] = embed[(size_t)idx*256 + tid];
  }
  __syncthreads();
  for (int ri=0; ri<8; ++ri){
    int r = ri*256 + tid;
    int d = r >> 10;
    int row = r & 1023;
    const float* wr = (d ? w_ih_b : w_ih_f) + (size_t)row*256;
    const float* bi = d ? b_ih_b : b_ih_f;
    const float* bh = d ? b_hh_b : b_hh_f;
    float acc[8];
    #pragma unroll
    for (int i=0;i<8;++i) acc[i]=0.f;
    for (int k0=0;k0<256;k0+=4){
      float4 p = *(const float4*)(wr + k0);
      #pragma unroll
      for (int i=0;i<8;++i){
        acc[i] += p.x*x_sh[i][k0] + p.y*x_sh[i][k0+1]
                + p.z*x_sh[i][k0+2] + p.w*x_sh[i][k0+3];
      }
    }
    float bias = bi[row] + bh[row];
    #pragma unroll
    for (int i=0;i<8;++i)
      xg[((size_t)d*LSEQ + (size_t)(t0+i))*1024 + row] = acc[i] + bias;
  }
}

// K2: bidirectional LSTM recurrence, 4 CUs/direction.
// Floor analysis (rounds 0-3): schedule changes moved nothing; the
// ~3000 cy/step floor is the exchange round trip at the MALL. This round:
// XCD-L2-scope atomics on both sides (see pub_fast/poll_fast). Blocks
// {0,8,16,24}=dir0, {1,9,17,25}=dir1 -> same-XCD under the round-robin
// bid->XCD mapping (supported by learn_hip m192's measured %8-swizzle win).
//  - FAST: publish global_atomic_swap_x2 (no sc1), poll global_atomic_add_x2
//    +0 sc0 (no sc1). Same XCD -> both RMW the same L2 line, RT ~200-300 cy.
//  - SLOW fallback: publisher ALSO atomicExch's the proven device-coherent
//    buffer; pollers demote permanently after 1024 fruitless fast spins
//    (~100 us one-time worst case). Hang-proof under a wrong mapping.
//    8B atomics can't tear; tag s written once per slot per parity cycle ->
//    no stale match. Parity-slot reuse induction holds per-buffer.
__global__ __launch_bounds__(256,1) void lstm_rec(
    const float* __restrict__ w_hh_f, const float* __restrict__ w_hh_b,
    const float* __restrict__ xg, unsigned short* __restrict__ hstH,
    u64* __restrict__ ex)
{
  int blk = blockIdx.x;
  int d = blk & 7;
  if (d > 1) return;
  int q = blk >> 3;                 // quad: owns units [64q, 64q+64)
  int qa = (q+1)&3, qb = (q+2)&3, qc = (q+3)&3;

  int tid = threadIdx.x;
  int g = tid >> 6, l = tid & 63;
  int row = g*256 + 64*q + l;       // gate rows (PyTorch order i,f,g,o)
  const float* W = d ? w_hh_b : w_hh_f;
  const float* xgd = xg + (size_t)d*LSEQ*1024;
  unsigned short* hd = hstH + (size_t)d*LSEQ*256;
  u64* exS = ex + (size_t)d*256;        // slow: [2 parity][128 pairs]
  u64* exF = ex + 512 + (size_t)d*256;  // fast (XCD L2): same layout

  __shared__ float gate_sh[2][256]; // parity-buffered [gate][64 units]
  __shared__ unsigned h2all[128];   // remote peers' packed f16 h-pairs

  // Permuted-column weights: w[0..31]=own pairs, then peers qa, qb, qc.
  half2v w[128];
  {
    const float* p0 = W + (size_t)row*256 + 64*q;
    const float* p1 = W + (size_t)row*256 + 64*qa;
    const float* p2 = W + (size_t)row*256 + 64*qb;
    const float* p3 = W + (size_t)row*256 + 64*qc;
    #pragma unroll
    for (int k0=0;k0<16;++k0){
      float4 a = *(const float4*)(p0+4*k0);
      w[2*k0]      = pack2(a.x,a.y);  w[2*k0+1]    = pack2(a.z,a.w);
      float4 b = *(const float4*)(p1+4*k0);
      w[32+2*k0]   = pack2(b.x,b.y);  w[32+2*k0+1] = pack2(b.z,b.w);
      float4 cc= *(const float4*)(p2+4*k0);
      w[64+2*k0]   = pack2(cc.x,cc.y); w[64+2*k0+1] = pack2(cc.z,cc.w);
      float4 e = *(const float4*)(p3+4*k0);
      w[96+2*k0]   = pack2(e.x,e.y);  w[96+2*k0+1] = pack2(e.z,e.w);
    }
  }
  if (tid < 128) h2all[tid] = 0u;
  float c0 = 0.f, c1 = 0.f;         // cell state: replicated, pair (l&31)
  unsigned hp = 0u;                 // own h-pair (l&31), replicated all lanes
  bool use_fast = true;             // per-thread demotion flag

  // loop-invariant addresses
  int pollj = tid - 64;                         // 0..95 for pollers
  int pollpeer = (q + 1 + (pollj>>5)) & 3;
  int pollslot = 32*pollpeer + (pollj & 31);    // valid when 64<=tid<160
  int adrA = (l < 32) ? (32*qa + l) : (32*qb + (l-32));
  int adrB = 32*qc + (l & 31);
  bool is_pub  = (tid < 32);                    // wave0 lanes 0-31: stores
  bool is_poll = (tid >= 64) && (tid < 160);    // waves 1-2: polls
  __syncthreads();

  int tf = d ? (LSEQ-1) : 0;
  float xg0 = xgd[(size_t)tf*1024 + row];

  for (int s=0;s<LSEQ;++s){
    bool p = is_poll && (s > 0);
    // --- local quarter dot: own 32 h-pairs straight from registers
    //     (lanes 0-31 hold pairs 0-31; readlane k<32 only touches those)
    float a0=xg0, a1=0.f, a2=0.f, a3=0.f;
    #pragma unroll
    for (int k=0;k<32;k+=4){
      unsigned p0v = __builtin_amdgcn_readlane(hp,k);
      unsigned p1v = __builtin_amdgcn_readlane(hp,k+1);
      unsigned p2v = __builtin_amdgcn_readlane(hp,k+2);
      unsigned p3v = __builtin_amdgcn_readlane(hp,k+3);
      a0 = __builtin_amdgcn_fdot2(__builtin_bit_cast(half2v,p0v), w[k],   a0, false);
      a1 = __builtin_amdgcn_fdot2(__builtin_bit_cast(half2v,p1v), w[k+1], a1, false);
      a2 = __builtin_amdgcn_fdot2(__builtin_bit_cast(half2v,p2v), w[k+2], a2, false);
      a3 = __builtin_amdgcn_fdot2(__builtin_bit_cast(half2v,p3v), w[k+3], a3, false);
    }
    // --- prefetch next xg (fire-and-forget; no vmcnt drain at barriers)
    float nxg = 0.f;
    if (s+1 < LSEQ){
      int tn = d ? (LSEQ-2-s) : (s+1);
      nxg = xgd[(size_t)tn*1024 + row];
    }
    // --- poll: fast XCD-L2 atomic spin, bounded; permanent demotion to the
    //     device-coherent slow buffer if the placement bet fails.
    if (p){
      u64 v = 0ull;
      if (use_fast){
        u64* fp = &exF[((s&1)<<7) + pollslot];
        int spins = 0;
        do {
          v = poll_fast(fp);
        } while ((unsigned)(v>>32) != (unsigned)s && ++spins < 1024);
        if ((unsigned)(v>>32) != (unsigned)s) use_fast = false;
      }
      if (!use_fast){
        while ((unsigned)(v>>32) != (unsigned)s)
          v = __hip_atomic_load(&exS[((s&1)<<7) + pollslot],
                                __ATOMIC_RELAXED, __HIP_MEMORY_SCOPE_AGENT);
      }
      h2all[pollslot] = (unsigned)v;
    }
    wg_barrier();                    // #1: pollers' LDS writes -> all waves
    // --- remote 3/4 dot: hrA lanes 0-31 = peer qa pairs, 32-63 = peer qb;
    //     hrB lanes 0-31 = peer qc pairs. All readlane/reg indices static.
    unsigned hrA = h2all[adrA];
    unsigned hrB = h2all[adrB];
    #pragma unroll
    for (int k=0;k<32;k+=2){
      unsigned pA0 = __builtin_amdgcn_readlane(hrA, k);
      unsigned pA1 = __builtin_amdgcn_readlane(hrA, k+1);
      unsigned pB0 = __builtin_amdgcn_readlane(hrA, 32+k);
      unsigned pB1 = __builtin_amdgcn_readlane(hrA, 32+k+1);
      unsigned pC0 = __builtin_amdgcn_readlane(hrB, k);
      unsigned pC1 = __builtin_amdgcn_readlane(hrB, k+1);
      a0 = __builtin_amdgcn_fdot2(__builtin_bit_cast(half2v,pA0), w[32+k],   a0, false);
      a1 = __builtin_amdgcn_fdot2(__builtin_bit_cast(half2v,pA1), w[32+k+1], a1, false);
      a2 = __builtin_amdgcn_fdot2(__builtin_bit_cast(half2v,pB0), w[64+k],   a2, false);
      a3 = __builtin_amdgcn_fdot2(__builtin_bit_cast(half2v,pB1), w[64+k+1], a3, false);
      a0 = __builtin_amdgcn_fdot2(__builtin_bit_cast(half2v,pC0), w[96+k],   a0, false);
      a1 = __builtin_amdgcn_fdot2(__builtin_bit_cast(half2v,pC1), w[96+k+1], a1, false);
    }
    float pre = (a0+a1) + (a2+a3);
    float act = (g==2) ? tanh_fast(pre) : sigm(pre);
    gate_sh[s&1][tid] = act;         // [g][64]: tid = g*64 + l
    wg_barrier();                    // #2: gate writes -> update reads
    // --- update, replicated on ALL lanes (deterministic -> identical hp)
    {
      int m = l & 31;
      const float* gp = gate_sh[s&1];
      float2 gi = *(const float2*)&gp[      2*m];
      float2 gf = *(const float2*)&gp[ 64 + 2*m];
      float2 gg = *(const float2*)&gp[128 + 2*m];
      float2 go = *(const float2*)&gp[192 + 2*m];
      c0 = gf.x*c0 + gi.x*gg.x;
      c1 = gf.y*c1 + gi.y*gg.y;
      float h0 = go.x * tanh_fast(c0);
      float h1 = go.y * tanh_fast(c1);
      hp = __builtin_bit_cast(unsigned, pack2(h0,h1));
    }
    // --- wave0: publish h(s) tagged s+1: fast XCD-L2 swap + coherent
    //     fallback copy; plus h history. All fire-and-forget.
    if (is_pub){
      if (s+1 < LSEQ){
        u64 pv = ((u64)(unsigned)(s+1) << 32) | (u64)hp;
        pub_fast(&exF[(((s+1)&1)<<7) + 32*q + tid], pv);
        atomicExch(&exS[(((s+1)&1)<<7) + 32*q + tid], pv);
      }
      int tp = d ? (LSEQ-1-s) : s;
      *(unsigned*)&hd[(size_t)tp*256 + 64*q + 2*tid] = hp;
    }
    xg0 = nxg;
    // no barrier #3: gate_sh is parity-buffered; h2all reads(s) and poller
    // writes(s+1) are separated by barrier #2(s); hp/c are registers.
  }
}

// K3: feats[t][tag] = b_out[tag] + [hf|hb] . w_out[tag]   (h history is f16)
__global__ void feats_kernel(
    const unsigned short* hstH, const float* w_out, const float* b_out,
    float* feats)
{
  __shared__ float w_sh[12*520];
  __shared__ float h_sh[16*520];
  const _Float16* hf = (const _Float16*)hstH;
  int tid=threadIdx.x;
  int t0=blockIdx.x*16;
  for (int i=tid;i<12*512;i+=256){ int tag=i>>9,k=i&511; w_sh[tag*520+k]=w_out[i]; }
  for (int i=tid;i<16*512;i+=256){
    int tt=i>>9,k=i&511;
    float v = (k<256)? (float)hf[(size_t)(t0+tt)*256+k]
                     : (float)hf[(size_t)(LSEQ+t0+tt)*256 + (k-256)];
    h_sh[tt*520+k]=v;
  }
  __syncthreads();
  if (tid<192){
    int tt=tid/12, tag=tid%12;
    const float* wr=&w_sh[tag*520];
    const float* hr=&h_sh[tt*520];
    float acc=b_out[tag];
    for (int k=0;k<512;k+=4){
      float4 a=*(const float4*)(wr+k);
      float4 b=*(const float4*)(hr+k);
      acc += a.x*b.x+a.y*b.y+a.z*b.z+a.w*b.w;
    }
    feats[(size_t)(t0+tt)*12+tag]=acc;
  }
}

// K4: Viterbi DP: feats in LDS, v register-resident via readlane; parallel
// block-composed backtrack.
__global__ void BiLSTM_CRF_14405320311361_kernel(
    const float* feats, const float* trans, float* outp)
{
  __shared__ float fsh[LSEQ*12];           // 96 KB
  __shared__ unsigned char bps[LSEQ*12];   // 24 KB
  __shared__ float term_sh[16];
  __shared__ int ibuf[66];
  __shared__ unsigned char fmap[64*12];
  int tid = threadIdx.x;
  for (int i=tid; i<LSEQ*12/4; i+=256)
    *(float4*)&fsh[4*i] = *(const float4*)&feats[4*i];
  __syncthreads();

  int lane = tid & 63;
  int fl = (lane<12) ? lane : 0;
  float vn = 0.f;
  if (tid < 64){
    float tr[12];
    #pragma unroll
    for (int p=0;p<12;++p) tr[p] = trans[fl*12+p];
    vn = (lane==10) ? 0.f : -10000.f;     // START=10
    float fa = fsh[fl];
    float fb = fsh[12+fl];
    for (int t=0;t<LSEQ;++t){
      unsigned vu = __float_as_uint(vn);
      float best; int bp; float sc;
      best = tr[0] + __uint_as_float(__builtin_amdgcn_readlane(vu,0)); bp = 0;
      sc = tr[1]  + __uint_as_float(__builtin_amdgcn_readlane(vu,1));  if(sc>best){best=sc;bp=1;}
      sc = tr[2]  + __uint_as_float(__builtin_amdgcn_readlane(vu,2));  if(sc>best){best=sc;bp=2;}
      sc = tr[3]  + __uint_as_float(__builtin_amdgcn_readlane(vu,3));  if(sc>best){best=sc;bp=3;}
      sc = tr[4]  + __uint_as_float(__builtin_amdgcn_readlane(vu,4));  if(sc>best){best=sc;bp=4;}
      sc = tr[5]  + __uint_as_float(__builtin_amdgcn_readlane(vu,5));  if(sc>best){best=sc;bp=5;}
      sc = tr[6]  + __uint_as_float(__builtin_amdgcn_readlane(vu,6));  if(sc>best){best=sc;bp=6;}
      sc = tr[7]  + __uint_as_float(__builtin_amdgcn_readlane(vu,7));  if(sc>best){best=sc;bp=7;}
      sc = tr[8]  + __uint_as_float(__builtin_amdgcn_readlane(vu,8));  if(sc>best){best=sc;bp=8;}
      sc = tr[9]  + __uint_as_float(__builtin_amdgcn_readlane(vu,9));  if(sc>best){best=sc;bp=9;}
      sc = tr[10] + __uint_as_float(__builtin_amdgcn_readlane(vu,10)); if(sc>best){best=sc;bp=10;}
      sc = tr[11] + __uint_as_float(__builtin_amdgcn_readlane(vu,11)); if(sc>best){best=sc;bp=11;}
      vn = best + fa;
      fa = fb;
      if (t+2 < LSEQ) fb = fsh[(t+2)*12+fl];
      if (lane<12) bps[t*12+lane] = (unsigned char)bp;
    }
  }
  if (tid < 12) term_sh[tid] = vn + trans[11*12+tid];   // STOP=11
  __syncthreads();
  if (tid == 0){
    float bs=term_sh[0]; int bt=0;
    for (int p=1;p<12;++p){ if (term_sh[p]>bs){bs=term_sh[p];bt=p;} }
    outp[0] = bs;
    ibuf[64] = bt;
  }
  __syncthreads();
  if (tid < 64){
    int b = tid;
    int f[12];
    int thi = b*32+31;
    #pragma unroll
    for (int x=0;x<12;++x) f[x] = bps[thi*12+x];
    for (int t=thi-1; t>=b*32; --t){
      int base = t*12;
      #pragma unroll
      for (int x=0;x<12;++x) f[x] = bps[base + f[x]];
    }
    #pragma unroll
    for (int x=0;x<12;++x) fmap[b*12+x] = (unsigned char)f[x];
  }
  __syncthreads();
  if (tid == 0){
    int tag = ibuf[64];
    for (int b=63;b>=0;--b){ ibuf[b]=tag; tag = fmap[b*12+tag]; }
  }
  __syncthreads();
  if (tid < 64){
    int b = tid;
    int tag = ibuf[b];
    for (int t=b*32+31; t>=b*32; --t){
      outp[1+t] = (float)tag;
      tag = bps[t*12+tag];
    }
  }
}

extern "C" void kernel_launch(void* const* d_in, const int* in_sizes, int n_in,
                              void* d_out, int out_size, void* d_ws, size_t ws_size,
                              hipStream_t stream) {
  const int*   sent   = (const int*)d_in[0];
  const float* embed  = (const float*)d_in[1];
  const float* w_ih_f = (const float*)d_in[2];
  const float* w_hh_f = (const float*)d_in[3];
  const float* b_ih_f = (const float*)d_in[4];
  const float* b_hh_f = (const float*)d_in[5];
  const float* w_ih_b = (const float*)d_in[6];
  const float* w_hh_b = (const float*)d_in[7];
  const float* b_ih_b = (const float*)d_in[8];
  const float* b_hh_b = (const float*)d_in[9];
  const float* w_out  = (const float*)d_in[10];
  const float* b_out  = (const float*)d_in[11];
  const float* trans  = (const float*)d_in[12];

  float* xg = (float*)d_ws;                                           // [2][L][1024] f32 = 16 MB
  unsigned short* hstH = (unsigned short*)(xg + (size_t)2*LSEQ*1024); // [2][L][256] f16 = 2 MB
  u64* ex = (u64*)(hstH + (size_t)2*LSEQ*256);                        // 8 KB (slow 512 + fast 512)
  float* feats = (float*)(ex + 1024);                                 // [L][12] f32 = 96 KB
  float* outp  = (float*)d_out;

  init_kernel<<<dim3(4), dim3(256), 0, stream>>>(ex);
  xg_kernel<<<dim3(LSEQ/8), dim3(256), 0, stream>>>(
      sent, embed, w_ih_f, b_ih_f, b_hh_f, w_ih_b, b_ih_b, b_hh_b, xg);
  lstm_rec<<<dim3(32), dim3(256), 0, stream>>>(w_hh_f, w_hh_b, xg, hstH, ex);
  feats_kernel<<<dim3(LSEQ/16), dim3(256), 0, stream>>>(hstH, w_out, b_out, feats);
  BiLSTM_CRF_14405320311361_kernel<<<dim3(1), dim3(256), 0, stream>>>(feats, trans, outp);
}

// Round 5
// 3515.468 us; speedup vs baseline: 1.0522x; 1.0522x over previous
//
#include <hip/hip_runtime.h>

#define LSEQ 2048
#define TAGS 12
#define NSLOT 128   // exchange ring depth (slots re-used after 128 steps)

typedef _Float16 half2v __attribute__((ext_vector_type(2)));
typedef unsigned long long u64;

__device__ __forceinline__ float sigm(float x){ return 1.0f/(1.0f+__expf(-x)); }
__device__ __forceinline__ float tanh_fast(float x){ return 1.0f - 2.0f/(1.0f+__expf(2.0f*x)); }
__device__ __forceinline__ half2v pack2(float a, float b){
  half2v r; r.x=(_Float16)a; r.y=(_Float16)b; return r;
}

// Raw workgroup barrier: orders LDS only (lgkmcnt), does NOT drain vmcnt.
__device__ __forceinline__ void wg_barrier(){
  asm volatile("s_waitcnt lgkmcnt(0)" ::: "memory");
  __builtin_amdgcn_s_barrier();
  __builtin_amdgcn_sched_barrier(0);
  asm volatile("" ::: "memory");
}

// ONE plain probe of a guaranteed-L1-cold line. L1 miss is mandatory
// (address untouched for >=128 steps, L1 cycles in ~20), so the load reads
// the XCD-shared L2 (~250 cy) where the publisher's sc0 write-through store
// landed (~150 cy after issue) -- IF publisher and poller share an XCD.
// Round-4 PMC proved atomics always pay the ~1000 cy memory-side RT; this
// is the only probe mechanism that can see fresh data at L2 latency.
__device__ __forceinline__ u64 probe_cold(const u64* p){
  u64 r;
  asm volatile("global_load_dwordx2 %0, %1, off\n\t"
               "s_waitcnt vmcnt(0)"
               : "=v"(r) : "v"(p) : "memory");
  return r;
}
__device__ __forceinline__ void store_pub(u64* p, u64 v){
  asm volatile("global_store_dwordx2 %0, %1, off sc0"
               :: "v"(p), "v"(v) : "memory");
}

// K0: zero exchange buffers: slow parity (1024 u64) + ring (NSLOT*256 u64).
__global__ void init_kernel(u64* ex)
{
  int tid = blockIdx.x*256 + threadIdx.x;
  if (tid < 1024 + NSLOT*256) ex[tid] = 0ull;
}

// K1: xg[d][t][row] = b_ih[row]+b_hh[row] + sum_e embed[sent[t]][e] * w_ih[row][e]
__global__ void xg_kernel(
    const int* sent, const float* embed,
    const float* w_ih_f, const float* b_ih_f, const float* b_hh_f,
    const float* w_ih_b, const float* b_ih_b, const float* b_hh_b,
    float* xg)
{
  __shared__ float x_sh[8][256];
  int tid = threadIdx.x;
  int t0 = blockIdx.x * 8;
  for (int i=0;i<8;++i){
    int idx = sent[t0+i];
    x_sh[i][tid] = embed[(size_t)idx*256 + tid];
  }
  __syncthreads();
  for (int ri=0; ri<8; ++ri){
    int r = ri*256 + tid;
    int d = r >> 10;
    int row = r & 1023;
    const float* wr = (d ? w_ih_b : w_ih_f) + (size_t)row*256;
    const float* bi = d ? b_ih_b : b_ih_f;
    const float* bh = d ? b_hh_b : b_hh_f;
    float acc[8];
    #pragma unroll
    for (int i=0;i<8;++i) acc[i]=0.f;
    for (int k0=0;k0<256;k0+=4){
      float4 p = *(const float4*)(wr + k0);
      #pragma unroll
      for (int i=0;i<8;++i){
        acc[i] += p.x*x_sh[i][k0] + p.y*x_sh[i][k0+1]
                + p.z*x_sh[i][k0+2] + p.w*x_sh[i][k0+3];
      }
    }
    float bias = bi[row] + bh[row];
    #pragma unroll
    for (int i=0;i<8;++i)
      xg[((size_t)d*LSEQ + (size_t)(t0+i))*1024 + row] = acc[i] + bias;
  }
}

// K2: bidirectional LSTM recurrence, 4 CUs/direction.
// Rounds 0-4 established: (a) schedule/barrier changes are perf-neutral;
// (b) atomics execute memory-side (~1000 cy RT) regardless of sc bits
// (round-4 WRITE_SIZE decomposition: polls found tags in ~1.2 spins, no
// speedup); (c) round-3's sc0-load fast path failed because PARITY-REUSED
// slots were already (stale) in the poller's L1. Exchange redesign:
//  - FAST: per-step ring slot (s & 127, 2 KB stride) -> poller's first
//    probe is guaranteed L1-cold -> reads XCD-shared L2 fresh (~250 cy).
//    Publisher: plain sc0 write-through store (~150 cy to L2). One probe
//    only (re-probing the now-cached line would hit stale L1).
//  - SLOW fallback per-step: proven atomicExch publish + agent-scope load
//    spin. Covers CU skew and a wrong XCD-mapping bet; hang-proof.
// Tag safety: 8B aligned single-instruction store can't tear; ring slot
// (s&127) stale content is tag s-128 != s; future tag s+128 impossible
// (publishers lead pollers by <=1 step). Slow parity-slot induction as
// before: C publishes s+1 only after consuming all s.
__global__ __launch_bounds__(256,1) void lstm_rec(
    const float* __restrict__ w_hh_f, const float* __restrict__ w_hh_b,
    const float* __restrict__ xg, unsigned short* __restrict__ hstH,
    u64* __restrict__ ex)
{
  int blk = blockIdx.x;
  int d = blk & 7;
  if (d > 1) return;
  int q = blk >> 3;                 // quad: owns units [64q, 64q+64)
  int qa = (q+1)&3, qb = (q+2)&3, qc = (q+3)&3;

  int tid = threadIdx.x;
  int g = tid >> 6, l = tid & 63;
  int row = g*256 + 64*q + l;       // gate rows (PyTorch order i,f,g,o)
  const float* W = d ? w_hh_b : w_hh_f;
  const float* xgd = xg + (size_t)d*LSEQ*1024;
  unsigned short* hd = hstH + (size_t)d*LSEQ*256;
  u64* exS = ex + (size_t)d*256;              // slow: [2 parity][128 pairs]
  u64* exFd = ex + 1024 + (size_t)d*128;      // ring: [NSLOT][2 dir][128]

  __shared__ float gate_sh[2][256]; // parity-buffered [gate][64 units]
  __shared__ unsigned h2all[128];   // remote peers' packed f16 h-pairs

  // Permuted-column weights: w[0..31]=own pairs, then peers qa, qb, qc.
  half2v w[128];
  {
    const float* p0 = W + (size_t)row*256 + 64*q;
    const float* p1 = W + (size_t)row*256 + 64*qa;
    const float* p2 = W + (size_t)row*256 + 64*qb;
    const float* p3 = W + (size_t)row*256 + 64*qc;
    #pragma unroll
    for (int k0=0;k0<16;++k0){
      float4 a = *(const float4*)(p0+4*k0);
      w[2*k0]      = pack2(a.x,a.y);  w[2*k0+1]    = pack2(a.z,a.w);
      float4 b = *(const float4*)(p1+4*k0);
      w[32+2*k0]   = pack2(b.x,b.y);  w[32+2*k0+1] = pack2(b.z,b.w);
      float4 cc= *(const float4*)(p2+4*k0);
      w[64+2*k0]   = pack2(cc.x,cc.y); w[64+2*k0+1] = pack2(cc.z,cc.w);
      float4 e = *(const float4*)(p3+4*k0);
      w[96+2*k0]   = pack2(e.x,e.y);  w[96+2*k0+1] = pack2(e.z,e.w);
    }
  }
  if (tid < 128) h2all[tid] = 0u;
  float c0 = 0.f, c1 = 0.f;         // cell state: replicated, pair (l&31)
  unsigned hp = 0u;                 // own h-pair (l&31), replicated all lanes

  // loop-invariant addresses
  int pollj = tid - 64;                         // 0..95 for pollers
  int pollpeer = (q + 1 + (pollj>>5)) & 3;
  int pollslot = 32*pollpeer + (pollj & 31);    // valid when 64<=tid<160
  int adrA = (l < 32) ? (32*qa + l) : (32*qb + (l-32));
  int adrB = 32*qc + (l & 31);
  bool is_pub  = (tid < 32);                    // wave0 lanes 0-31: stores
  bool is_poll = (tid >= 64) && (tid < 160);    // waves 1-2: polls
  __syncthreads();

  int tf = d ? (LSEQ-1) : 0;
  float xg0 = xgd[(size_t)tf*1024 + row];

  for (int s=0;s<LSEQ;++s){
    bool p = is_poll && (s > 0);
    // --- local quarter dot: own 32 h-pairs straight from registers
    //     (lanes 0-31 hold pairs 0-31; readlane k<32 only touches those).
    //     ~300 cy: also serves as skew tolerance before the single probe.
    float a0=xg0, a1=0.f, a2=0.f, a3=0.f;
    #pragma unroll
    for (int k=0;k<32;k+=4){
      unsigned p0v = __builtin_amdgcn_readlane(hp,k);
      unsigned p1v = __builtin_amdgcn_readlane(hp,k+1);
      unsigned p2v = __builtin_amdgcn_readlane(hp,k+2);
      unsigned p3v = __builtin_amdgcn_readlane(hp,k+3);
      a0 = __builtin_amdgcn_fdot2(__builtin_bit_cast(half2v,p0v), w[k],   a0, false);
      a1 = __builtin_amdgcn_fdot2(__builtin_bit_cast(half2v,p1v), w[k+1], a1, false);
      a2 = __builtin_amdgcn_fdot2(__builtin_bit_cast(half2v,p2v), w[k+2], a2, false);
      a3 = __builtin_amdgcn_fdot2(__builtin_bit_cast(half2v,p3v), w[k+3], a3, false);
    }
    // --- poll: ONE cold-line probe (L2-latency detect in the common case),
    //     then the proven device-coherent slow spin only on a miss.
    if (p){
      u64 v = probe_cold(&exFd[(((unsigned)s & (NSLOT-1))<<8) + pollslot]);
      if ((unsigned)(v>>32) != (unsigned)s){
        do {
          v = __hip_atomic_load(&exS[((s&1)<<7) + pollslot],
                                __ATOMIC_RELAXED, __HIP_MEMORY_SCOPE_AGENT);
        } while ((unsigned)(v>>32) != (unsigned)s);
      }
      h2all[pollslot] = (unsigned)v;
    }
    // --- prefetch next xg AFTER the probe so the probe's vmcnt wait never
    //     drains this slow load; it has the remote dot + next local dot to
    //     complete (fire-and-forget; barriers don't drain vmcnt).
    float nxg = 0.f;
    if (s+1 < LSEQ){
      int tn = d ? (LSEQ-2-s) : (s+1);
      nxg = xgd[(size_t)tn*1024 + row];
    }
    wg_barrier();                    // #1: pollers' LDS writes -> all waves
    // --- remote 3/4 dot: hrA lanes 0-31 = peer qa pairs, 32-63 = peer qb;
    //     hrB lanes 0-31 = peer qc pairs. All readlane/reg indices static.
    unsigned hrA = h2all[adrA];
    unsigned hrB = h2all[adrB];
    #pragma unroll
    for (int k=0;k<32;k+=2){
      unsigned pA0 = __builtin_amdgcn_readlane(hrA, k);
      unsigned pA1 = __builtin_amdgcn_readlane(hrA, k+1);
      unsigned pB0 = __builtin_amdgcn_readlane(hrA, 32+k);
      unsigned pB1 = __builtin_amdgcn_readlane(hrA, 32+k+1);
      unsigned pC0 = __builtin_amdgcn_readlane(hrB, k);
      unsigned pC1 = __builtin_amdgcn_readlane(hrB, k+1);
      a0 = __builtin_amdgcn_fdot2(__builtin_bit_cast(half2v,pA0), w[32+k],   a0, false);
      a1 = __builtin_amdgcn_fdot2(__builtin_bit_cast(half2v,pA1), w[32+k+1], a1, false);
      a2 = __builtin_amdgcn_fdot2(__builtin_bit_cast(half2v,pB0), w[64+k],   a2, false);
      a3 = __builtin_amdgcn_fdot2(__builtin_bit_cast(half2v,pB1), w[64+k+1], a3, false);
      a0 = __builtin_amdgcn_fdot2(__builtin_bit_cast(half2v,pC0), w[96+k],   a0, false);
      a1 = __builtin_amdgcn_fdot2(__builtin_bit_cast(half2v,pC1), w[96+k+1], a1, false);
    }
    float pre = (a0+a1) + (a2+a3);
    float act = (g==2) ? tanh_fast(pre) : sigm(pre);
    gate_sh[s&1][tid] = act;         // [g][64]: tid = g*64 + l
    wg_barrier();                    // #2: gate writes -> update reads
    // --- update, replicated on ALL lanes (deterministic -> identical hp)
    {
      int m = l & 31;
      const float* gp = gate_sh[s&1];
      float2 gi = *(const float2*)&gp[      2*m];
      float2 gf = *(const float2*)&gp[ 64 + 2*m];
      float2 gg = *(const float2*)&gp[128 + 2*m];
      float2 go = *(const float2*)&gp[192 + 2*m];
      c0 = gf.x*c0 + gi.x*gg.x;
      c1 = gf.y*c1 + gi.y*gg.y;
      float h0 = go.x * tanh_fast(c0);
      float h1 = go.y * tanh_fast(c1);
      hp = __builtin_bit_cast(unsigned, pack2(h0,h1));
    }
    // --- wave0: publish h(s) tagged s+1: ring sc0 store (fast, to XCD L2)
    //     then coherent atomicExch fallback; plus h history. Fire-and-forget.
    if (is_pub){
      if (s+1 < LSEQ){
        u64 pv = ((u64)(unsigned)(s+1) << 32) | (u64)hp;
        store_pub(&exFd[(((unsigned)(s+1) & (NSLOT-1))<<8) + 32*q + tid], pv);
        atomicExch(&exS[(((s+1)&1)<<7) + 32*q + tid], pv);
      }
      int tp = d ? (LSEQ-1-s) : s;
      *(unsigned*)&hd[(size_t)tp*256 + 64*q + 2*tid] = hp;
    }
    xg0 = nxg;
    // no barrier #3: gate_sh is parity-buffered; h2all reads(s) and poller
    // writes(s+1) are separated by barrier #2(s); hp/c are registers.
  }
}

// K3: feats[t][tag] = b_out[tag] + [hf|hb] . w_out[tag]   (h history is f16)
__global__ void feats_kernel(
    const unsigned short* hstH, const float* w_out, const float* b_out,
    float* feats)
{
  __shared__ float w_sh[12*520];
  __shared__ float h_sh[16*520];
  const _Float16* hf = (const _Float16*)hstH;
  int tid=threadIdx.x;
  int t0=blockIdx.x*16;
  for (int i=tid;i<12*512;i+=256){ int tag=i>>9,k=i&511; w_sh[tag*520+k]=w_out[i]; }
  for (int i=tid;i<16*512;i+=256){
    int tt=i>>9,k=i&511;
    float v = (k<256)? (float)hf[(size_t)(t0+tt)*256+k]
                     : (float)hf[(size_t)(LSEQ+t0+tt)*256 + (k-256)];
    h_sh[tt*520+k]=v;
  }
  __syncthreads();
  if (tid<192){
    int tt=tid/12, tag=tid%12;
    const float* wr=&w_sh[tag*520];
    const float* hr=&h_sh[tt*520];
    float acc=b_out[tag];
    for (int k=0;k<512;k+=4){
      float4 a=*(const float4*)(wr+k);
      float4 b=*(const float4*)(hr+k);
      acc += a.x*b.x+a.y*b.y+a.z*b.z+a.w*b.w;
    }
    feats[(size_t)(t0+tt)*12+tag]=acc;
  }
}

// K4: Viterbi DP: feats in LDS, v register-resident via readlane; parallel
// block-composed backtrack.
__global__ void BiLSTM_CRF_14405320311361_kernel(
    const float* feats, const float* trans, float* outp)
{
  __shared__ float fsh[LSEQ*12];           // 96 KB
  __shared__ unsigned char bps[LSEQ*12];   // 24 KB
  __shared__ float term_sh[16];
  __shared__ int ibuf[66];
  __shared__ unsigned char fmap[64*12];
  int tid = threadIdx.x;
  for (int i=tid; i<LSEQ*12/4; i+=256)
    *(float4*)&fsh[4*i] = *(const float4*)&feats[4*i];
  __syncthreads();

  int lane = tid & 63;
  int fl = (lane<12) ? lane : 0;
  float vn = 0.f;
  if (tid < 64){
    float tr[12];
    #pragma unroll
    for (int p=0;p<12;++p) tr[p] = trans[fl*12+p];
    vn = (lane==10) ? 0.f : -10000.f;     // START=10
    float fa = fsh[fl];
    float fb = fsh[12+fl];
    for (int t=0;t<LSEQ;++t){
      unsigned vu = __float_as_uint(vn);
      float best; int bp; float sc;
      best = tr[0] + __uint_as_float(__builtin_amdgcn_readlane(vu,0)); bp = 0;
      sc = tr[1]  + __uint_as_float(__builtin_amdgcn_readlane(vu,1));  if(sc>best){best=sc;bp=1;}
      sc = tr[2]  + __uint_as_float(__builtin_amdgcn_readlane(vu,2));  if(sc>best){best=sc;bp=2;}
      sc = tr[3]  + __uint_as_float(__builtin_amdgcn_readlane(vu,3));  if(sc>best){best=sc;bp=3;}
      sc = tr[4]  + __uint_as_float(__builtin_amdgcn_readlane(vu,4));  if(sc>best){best=sc;bp=4;}
      sc = tr[5]  + __uint_as_float(__builtin_amdgcn_readlane(vu,5));  if(sc>best){best=sc;bp=5;}
      sc = tr[6]  + __uint_as_float(__builtin_amdgcn_readlane(vu,6));  if(sc>best){best=sc;bp=6;}
      sc = tr[7]  + __uint_as_float(__builtin_amdgcn_readlane(vu,7));  if(sc>best){best=sc;bp=7;}
      sc = tr[8]  + __uint_as_float(__builtin_amdgcn_readlane(vu,8));  if(sc>best){best=sc;bp=8;}
      sc = tr[9]  + __uint_as_float(__builtin_amdgcn_readlane(vu,9));  if(sc>best){best=sc;bp=9;}
      sc = tr[10] + __uint_as_float(__builtin_amdgcn_readlane(vu,10)); if(sc>best){best=sc;bp=10;}
      sc = tr[11] + __uint_as_float(__builtin_amdgcn_readlane(vu,11)); if(sc>best){best=sc;bp=11;}
      vn = best + fa;
      fa = fb;
      if (t+2 < LSEQ) fb = fsh[(t+2)*12+fl];
      if (lane<12) bps[t*12+lane] = (unsigned char)bp;
    }
  }
  if (tid < 12) term_sh[tid] = vn + trans[11*12+tid];   // STOP=11
  __syncthreads();
  if (tid == 0){
    float bs=term_sh[0]; int bt=0;
    for (int p=1;p<12;++p){ if (term_sh[p]>bs){bs=term_sh[p];bt=p;} }
    outp[0] = bs;
    ibuf[64] = bt;
  }
  __syncthreads();
  if (tid < 64){
    int b = tid;
    int f[12];
    int thi = b*32+31;
    #pragma unroll
    for (int x=0;x<12;++x) f[x] = bps[thi*12+x];
    for (int t=thi-1; t>=b*32; --t){
      int base = t*12;
      #pragma unroll
      for (int x=0;x<12;++x) f[x] = bps[base + f[x]];
    }
    #pragma unroll
    for (int x=0;x<12;++x) fmap[b*12+x] = (unsigned char)f[x];
  }
  __syncthreads();
  if (tid == 0){
    int tag = ibuf[64];
    for (int b=63;b>=0;--b){ ibuf[b]=tag; tag = fmap[b*12+tag]; }
  }
  __syncthreads();
  if (tid < 64){
    int b = tid;
    int tag = ibuf[b];
    for (int t=b*32+31; t>=b*32; --t){
      outp[1+t] = (float)tag;
      tag = bps[t*12+tag];
    }
  }
}

extern "C" void kernel_launch(void* const* d_in, const int* in_sizes, int n_in,
                              void* d_out, int out_size, void* d_ws, size_t ws_size,
                              hipStream_t stream) {
  const int*   sent   = (const int*)d_in[0];
  const float* embed  = (const float*)d_in[1];
  const float* w_ih_f = (const float*)d_in[2];
  const float* w_hh_f = (const float*)d_in[3];
  const float* b_ih_f = (const float*)d_in[4];
  const float* b_hh_f = (const float*)d_in[5];
  const float* w_ih_b = (const float*)d_in[6];
  const float* w_hh_b = (const float*)d_in[7];
  const float* b_ih_b = (const float*)d_in[8];
  const float* b_hh_b = (const float*)d_in[9];
  const float* w_out  = (const float*)d_in[10];
  const float* b_out  = (const float*)d_in[11];
  const float* trans  = (const float*)d_in[12];

  float* xg = (float*)d_ws;                                           // [2][L][1024] f32 = 16 MB
  unsigned short* hstH = (unsigned short*)(xg + (size_t)2*LSEQ*1024); // [2][L][256] f16 = 2 MB
  u64* ex = (u64*)(hstH + (size_t)2*LSEQ*256);      // slow 1024 u64 + ring NSLOT*256 u64 = 264 KB
  float* feats = (float*)(ex + 1024 + NSLOT*256);                     // [L][12] f32 = 96 KB
  float* outp  = (float*)d_out;

  init_kernel<<<dim3((1024 + NSLOT*256)/256), dim3(256), 0, stream>>>(ex);
  xg_kernel<<<dim3(LSEQ/8), dim3(256), 0, stream>>>(
      sent, embed, w_ih_f, b_ih_f, b_hh_f, w_ih_b, b_ih_b, b_hh_b, xg);
  lstm_rec<<<dim3(32), dim3(256), 0, stream>>>(w_hh_f, w_hh_b, xg, hstH, ex);
  feats_kernel<<<dim3(LSEQ/16), dim3(256), 0, stream>>>(hstH, w_out, b_out, feats);
  BiLSTM_CRF_14405320311361_kernel<<<dim3(1), dim3(256), 0, stream>>>(feats, trans, outp);
}

// Round 6
// 3423.421 us; speedup vs baseline: 1.0804x; 1.0269x over previous
//
#include <hip/hip_runtime.h>

#define LSEQ 2048
#define TAGS 12
#define NSLOT 128   // exchange ring depth (slots re-used after 128 steps)
#define NBLK 32     // blocks launched for election (8 survive)

typedef _Float16 half2v __attribute__((ext_vector_type(2)));
typedef unsigned long long u64;

__device__ __forceinline__ float sigm(float x){ return 1.0f/(1.0f+__expf(-x)); }
__device__ __forceinline__ float tanh_fast(float x){ return 1.0f - 2.0f/(1.0f+__expf(2.0f*x)); }
__device__ __forceinline__ half2v pack2(float a, float b){
  half2v r; r.x=(_Float16)a; r.y=(_Float16)b; return r;
}

// Raw workgroup barrier: orders LDS only (lgkmcnt), does NOT drain vmcnt.
__device__ __forceinline__ void wg_barrier(){
  asm volatile("s_waitcnt lgkmcnt(0)" ::: "memory");
  __builtin_amdgcn_s_barrier();
  __builtin_amdgcn_sched_barrier(0);
  asm volatile("" ::: "memory");
}

// sc0 store: L1-write-through into the issuing CU's XCD L2 (~150 cy).
__device__ __forceinline__ void store_pub(u64* p, u64 v){
  asm volatile("global_store_dwordx2 %0, %1, off sc0"
               :: "v"(p), "v"(v) : "memory");
}

// K0: zero exchange buffers: slow parity (1024) + ring (NSLOT*256) + rtab (32).
__global__ void init_kernel(u64* ex)
{
  int tid = blockIdx.x*256 + threadIdx.x;
  if (tid < 1024 + NSLOT*256 + NBLK) ex[tid] = 0ull;
}

// K1: xg[d][t][row] = b_ih[row]+b_hh[row] + sum_e embed[sent[t]][e] * w_ih[row][e]
__global__ void xg_kernel(
    const int* sent, const float* embed,
    const float* w_ih_f, const float* b_ih_f, const float* b_hh_f,
    const float* w_ih_b, const float* b_ih_b, const float* b_hh_b,
    float* xg)
{
  __shared__ float x_sh[8][256];
  int tid = threadIdx.x;
  int t0 = blockIdx.x * 8;
  for (int i=0;i<8;++i){
    int idx = sent[t0+i];
    x_sh[i][tid] = embed[(size_t)idx*256 + tid];
  }
  __syncthreads();
  for (int ri=0; ri<8; ++ri){
    int r = ri*256 + tid;
    int d = r >> 10;
    int row = r & 1023;
    const float* wr = (d ? w_ih_b : w_ih_f) + (size_t)row*256;
    const float* bi = d ? b_ih_b : b_ih_f;
    const float* bh = d ? b_hh_b : b_hh_f;
    float acc[8];
    #pragma unroll
    for (int i=0;i<8;++i) acc[i]=0.f;
    for (int k0=0;k0<256;k0+=4){
      float4 p = *(const float4*)(wr + k0);
      #pragma unroll
      for (int i=0;i<8;++i){
        acc[i] += p.x*x_sh[i][k0] + p.y*x_sh[i][k0+1]
                + p.z*x_sh[i][k0+2] + p.w*x_sh[i][k0+3];
      }
    }
    float bias = bi[row] + bh[row];
    #pragma unroll
    for (int i=0;i<8;++i)
      xg[((size_t)d*LSEQ + (size_t)(t0+i))*1024 + row] = acc[i] + bias;
  }
}

// K2: bidirectional LSTM recurrence, 4 CUs/direction.
// Evidence chain (rounds 0-5): all five exchange variants land 2840-3130 us
// because publisher and poller were never actually on the same XCD: round-3's
// demotion cost (+210 us / 2048 spins = ~246 cy/spin = L2-hit latency) proves
// sc0 loads bypassed L1 and spun on an L2 that never received the publisher's
// sc0 store -> the %8 block->XCD co-location bet is WRONG, and every variant
// actually ran the ~1000 cy MALL round trip.
// This round: RUNTIME XCD ELECTION. Each of 32 blocks reads HW_REG_XCC_ID
// (s_getreg, learn_hip m09), publishes it (device atomicExch), reads all 32
// (hang-free: publish precedes any wait), and computes the same deterministic
// grouping: dir0 = first 4 blocks sharing an XCD, dir1 = next 4 (pigeonhole
// on 32 blocks / 8 XCDs guarantees both groups under ANY mapping). 24 exit.
// Same-XCD now guaranteed -> sc0 exchange finally operates:
//  - publish: sc0 write-through store to ring slot (s&127; never-reused line
//    -> no stale-L1 hazard even if a load slips past sc0).
//  - poll: sc0 L1-bypass load of the SAME physical L2 (~250 cy RT, measured
//    in round 3). Probe issued BEFORE the local dot, checked after it with a
//    counted vmcnt(1) (xg prefetch issued in between stays in flight).
//  - demotion fallback: 512 spins then the proven atomicExch/agent-load slow
//    path, permanent demote -> worst case = baseline + ~130 us, hang-proof.
// Tag safety: 8B store can't tear; ring slot stale tag is s-128 != s; future
// tag impossible (publishers lead pollers by <=1 step).
__global__ __launch_bounds__(256,1) void lstm_rec(
    const float* __restrict__ w_hh_f, const float* __restrict__ w_hh_b,
    const float* __restrict__ xg, unsigned short* __restrict__ hstH,
    u64* __restrict__ ex)
{
  int blk = blockIdx.x;
  int tid = threadIdx.x;
  u64* rtab = ex + 1024 + NSLOT*256;   // [NBLK] election table

  __shared__ int role_sh[2];
  if (tid == 0){
    unsigned xcc;
    asm volatile("s_getreg_b32 %0, hwreg(HW_REG_XCC_ID)" : "=s"(xcc));
    xcc &= 15u;
    atomicExch(&rtab[blk], 0x100ull | (u64)xcc);   // bit8 = valid
    unsigned xs[NBLK];
    for (int i=0;i<NBLK;++i){
      u64 v;
      do {
        v = __hip_atomic_load(&rtab[i], __ATOMIC_RELAXED, __HIP_MEMORY_SCOPE_AGENT);
      } while (!(v & 0x100ull));
      xs[i] = (unsigned)v & 15u;
    }
    int dd = -1, qq = -1;
    unsigned taken = 0u;
    for (int dir = 0; dir < 2; ++dir){
      int pick = -1;
      for (int x = 0; x < 16 && pick < 0; ++x){
        int cnt = 0;
        for (int i=0;i<NBLK;++i)
          if (!((taken>>i)&1u) && xs[i]==(unsigned)x) ++cnt;
        if (cnt >= 4) pick = x;
      }
      int rank = 0;
      for (int i=0;i<NBLK && rank<4;++i){
        if (!((taken>>i)&1u) && pick >= 0 && xs[i]==(unsigned)pick){
          if (i == blk){ dd = dir; qq = rank; }
          taken |= 1u<<i; ++rank;
        }
      }
    }
    role_sh[0] = dd; role_sh[1] = qq;
  }
  __syncthreads();
  int d = role_sh[0];
  int q = role_sh[1];
  if (d < 0) return;                // 24 non-elected blocks exit

  int qa = (q+1)&3, qb = (q+2)&3, qc = (q+3)&3;
  int g = tid >> 6, l = tid & 63;
  int row = g*256 + 64*q + l;       // gate rows (PyTorch order i,f,g,o)
  const float* W = d ? w_hh_b : w_hh_f;
  const float* xgd = xg + (size_t)d*LSEQ*1024;
  unsigned short* hd = hstH + (size_t)d*LSEQ*256;
  u64* exS = ex + (size_t)d*256;              // slow: [2 parity][128 pairs]
  u64* exFd = ex + 1024 + (size_t)d*128;      // ring: [NSLOT][2 dir][128]

  __shared__ float gate_sh[2][256]; // parity-buffered [gate][64 units]
  __shared__ unsigned h2all[128];   // remote peers' packed f16 h-pairs

  // Permuted-column weights: w[0..31]=own pairs, then peers qa, qb, qc.
  half2v w[128];
  {
    const float* p0 = W + (size_t)row*256 + 64*q;
    const float* p1 = W + (size_t)row*256 + 64*qa;
    const float* p2 = W + (size_t)row*256 + 64*qb;
    const float* p3 = W + (size_t)row*256 + 64*qc;
    #pragma unroll
    for (int k0=0;k0<16;++k0){
      float4 a = *(const float4*)(p0+4*k0);
      w[2*k0]      = pack2(a.x,a.y);  w[2*k0+1]    = pack2(a.z,a.w);
      float4 b = *(const float4*)(p1+4*k0);
      w[32+2*k0]   = pack2(b.x,b.y);  w[32+2*k0+1] = pack2(b.z,b.w);
      float4 cc= *(const float4*)(p2+4*k0);
      w[64+2*k0]   = pack2(cc.x,cc.y); w[64+2*k0+1] = pack2(cc.z,cc.w);
      float4 e = *(const float4*)(p3+4*k0);
      w[96+2*k0]   = pack2(e.x,e.y);  w[96+2*k0+1] = pack2(e.z,e.w);
    }
  }
  if (tid < 128) h2all[tid] = 0u;
  float c0 = 0.f, c1 = 0.f;         // cell state: replicated, pair (l&31)
  unsigned hp = 0u;                 // own h-pair (l&31), replicated all lanes
  bool use_fast = true;             // per-thread demotion flag

  // loop-invariant addresses
  int pollj = tid - 64;                         // 0..95 for pollers
  int pollpeer = (q + 1 + (pollj>>5)) & 3;
  int pollslot = 32*pollpeer + (pollj & 31);    // valid when 64<=tid<160
  int adrA = (l < 32) ? (32*qa + l) : (32*qb + (l-32));
  int adrB = 32*qc + (l & 31);
  bool is_pub  = (tid < 32);                    // wave0 lanes 0-31: stores
  bool is_poll = (tid >= 64) && (tid < 160);    // waves 1-2: polls
  __syncthreads();

  int tf = d ? (LSEQ-1) : 0;
  float xg0 = xgd[(size_t)tf*1024 + row];

  for (int s=0;s<LSEQ;++s){
    bool p = is_poll && (s > 0);
    // --- probe issue BEFORE local dot: its L2 RT hides under the dot.
    //     "+v" with pre-zeroed pair: a premature read sees tag 0 -> safe.
    u64 pv_ = 0ull;
    u64* fp = &exFd[(((unsigned)s & (NSLOT-1))<<8) + pollslot];
    if (p && use_fast){
      asm volatile("global_load_dwordx2 %0, %1, off sc0"
                   : "+v"(pv_) : "v"(fp) : "memory");
    }
    // --- xg prefetch (issued after probe -> vmcnt(1) below waits probe only)
    float nxg = 0.f;
    if (s+1 < LSEQ){
      int tn = d ? (LSEQ-2-s) : (s+1);
      nxg = xgd[(size_t)tn*1024 + row];
    }
    // --- local quarter dot: own 32 h-pairs straight from registers
    float a0=xg0, a1=0.f, a2=0.f, a3=0.f;
    #pragma unroll
    for (int k=0;k<32;k+=4){
      unsigned p0v = __builtin_amdgcn_readlane(hp,k);
      unsigned p1v = __builtin_amdgcn_readlane(hp,k+1);
      unsigned p2v = __builtin_amdgcn_readlane(hp,k+2);
      unsigned p3v = __builtin_amdgcn_readlane(hp,k+3);
      a0 = __builtin_amdgcn_fdot2(__builtin_bit_cast(half2v,p0v), w[k],   a0, false);
      a1 = __builtin_amdgcn_fdot2(__builtin_bit_cast(half2v,p1v), w[k+1], a1, false);
      a2 = __builtin_amdgcn_fdot2(__builtin_bit_cast(half2v,p2v), w[k+2], a2, false);
      a3 = __builtin_amdgcn_fdot2(__builtin_bit_cast(half2v,p3v), w[k+3], a3, false);
    }
    // --- poll check: counted wait (probe is the oldest outstanding VMEM),
    //     short sc0 re-probe spin, then permanent demote to slow path.
    if (p){
      u64 v = 0ull;
      if (use_fast){
        asm volatile("s_waitcnt vmcnt(1)" : "+v"(pv_) :: "memory");
        v = pv_;
        int spins = 0;
        while ((unsigned)(v>>32) != (unsigned)s && spins < 512){
          asm volatile("global_load_dwordx2 %0, %1, off sc0\n\t"
                       "s_waitcnt vmcnt(0)"
                       : "+v"(v) : "v"(fp) : "memory");
          ++spins;
        }
        if ((unsigned)(v>>32) != (unsigned)s) use_fast = false;
      }
      if (!use_fast){
        while ((unsigned)(v>>32) != (unsigned)s)
          v = __hip_atomic_load(&exS[((s&1)<<7) + pollslot],
                                __ATOMIC_RELAXED, __HIP_MEMORY_SCOPE_AGENT);
      }
      h2all[pollslot] = (unsigned)v;
    }
    wg_barrier();                    // #1: pollers' LDS writes -> all waves
    // --- remote 3/4 dot: hrA lanes 0-31 = peer qa pairs, 32-63 = peer qb;
    //     hrB lanes 0-31 = peer qc pairs. All readlane/reg indices static.
    unsigned hrA = h2all[adrA];
    unsigned hrB = h2all[adrB];
    #pragma unroll
    for (int k=0;k<32;k+=2){
      unsigned pA0 = __builtin_amdgcn_readlane(hrA, k);
      unsigned pA1 = __builtin_amdgcn_readlane(hrA, k+1);
      unsigned pB0 = __builtin_amdgcn_readlane(hrA, 32+k);
      unsigned pB1 = __builtin_amdgcn_readlane(hrA, 32+k+1);
      unsigned pC0 = __builtin_amdgcn_readlane(hrB, k);
      unsigned pC1 = __builtin_amdgcn_readlane(hrB, k+1);
      a0 = __builtin_amdgcn_fdot2(__builtin_bit_cast(half2v,pA0), w[32+k],   a0, false);
      a1 = __builtin_amdgcn_fdot2(__builtin_bit_cast(half2v,pA1), w[32+k+1], a1, false);
      a2 = __builtin_amdgcn_fdot2(__builtin_bit_cast(half2v,pB0), w[64+k],   a2, false);
      a3 = __builtin_amdgcn_fdot2(__builtin_bit_cast(half2v,pB1), w[64+k+1], a3, false);
      a0 = __builtin_amdgcn_fdot2(__builtin_bit_cast(half2v,pC0), w[96+k],   a0, false);
      a1 = __builtin_amdgcn_fdot2(__builtin_bit_cast(half2v,pC1), w[96+k+1], a1, false);
    }
    float pre = (a0+a1) + (a2+a3);
    float act = (g==2) ? tanh_fast(pre) : sigm(pre);
    gate_sh[s&1][tid] = act;         // [g][64]: tid = g*64 + l
    wg_barrier();                    // #2: gate writes -> update reads
    // --- update, replicated on ALL lanes (deterministic -> identical hp)
    {
      int m = l & 31;
      const float* gp = gate_sh[s&1];
      float2 gi = *(const float2*)&gp[      2*m];
      float2 gf = *(const float2*)&gp[ 64 + 2*m];
      float2 gg = *(const float2*)&gp[128 + 2*m];
      float2 go = *(const float2*)&gp[192 + 2*m];
      c0 = gf.x*c0 + gi.x*gg.x;
      c1 = gf.y*c1 + gi.y*gg.y;
      float h0 = go.x * tanh_fast(c0);
      float h1 = go.y * tanh_fast(c1);
      hp = __builtin_bit_cast(unsigned, pack2(h0,h1));
    }
    // --- wave0: publish h(s) tagged s+1: ring sc0 store (same-XCD L2 by
    //     election) + coherent atomicExch fallback; plus h history.
    if (is_pub){
      if (s+1 < LSEQ){
        u64 pv = ((u64)(unsigned)(s+1) << 32) | (u64)hp;
        store_pub(&exFd[(((unsigned)(s+1) & (NSLOT-1))<<8) + 32*q + tid], pv);
        atomicExch(&exS[(((s+1)&1)<<7) + 32*q + tid], pv);
      }
      int tp = d ? (LSEQ-1-s) : s;
      *(unsigned*)&hd[(size_t)tp*256 + 64*q + 2*tid] = hp;
    }
    xg0 = nxg;
    // no barrier #3: gate_sh is parity-buffered; h2all reads(s) and poller
    // writes(s+1) are separated by barrier #2(s); hp/c are registers.
  }
}

// K3: feats[t][tag] = b_out[tag] + [hf|hb] . w_out[tag]   (h history is f16)
__global__ void feats_kernel(
    const unsigned short* hstH, const float* w_out, const float* b_out,
    float* feats)
{
  __shared__ float w_sh[12*520];
  __shared__ float h_sh[16*520];
  const _Float16* hf = (const _Float16*)hstH;
  int tid=threadIdx.x;
  int t0=blockIdx.x*16;
  for (int i=tid;i<12*512;i+=256){ int tag=i>>9,k=i&511; w_sh[tag*520+k]=w_out[i]; }
  for (int i=tid;i<16*512;i+=256){
    int tt=i>>9,k=i&511;
    float v = (k<256)? (float)hf[(size_t)(t0+tt)*256+k]
                     : (float)hf[(size_t)(LSEQ+t0+tt)*256 + (k-256)];
    h_sh[tt*520+k]=v;
  }
  __syncthreads();
  if (tid<192){
    int tt=tid/12, tag=tid%12;
    const float* wr=&w_sh[tag*520];
    const float* hr=&h_sh[tt*520];
    float acc=b_out[tag];
    for (int k=0;k<512;k+=4){
      float4 a=*(const float4*)(wr+k);
      float4 b=*(const float4*)(hr+k);
      acc += a.x*b.x+a.y*b.y+a.z*b.z+a.w*b.w;
    }
    feats[(size_t)(t0+tt)*12+tag]=acc;
  }
}

// K4: Viterbi DP: feats in LDS, v register-resident via readlane; parallel
// block-composed backtrack.
__global__ void BiLSTM_CRF_14405320311361_kernel(
    const float* feats, const float* trans, float* outp)
{
  __shared__ float fsh[LSEQ*12];           // 96 KB
  __shared__ unsigned char bps[LSEQ*12];   // 24 KB
  __shared__ float term_sh[16];
  __shared__ int ibuf[66];
  __shared__ unsigned char fmap[64*12];
  int tid = threadIdx.x;
  for (int i=tid; i<LSEQ*12/4; i+=256)
    *(float4*)&fsh[4*i] = *(const float4*)&feats[4*i];
  __syncthreads();

  int lane = tid & 63;
  int fl = (lane<12) ? lane : 0;
  float vn = 0.f;
  if (tid < 64){
    float tr[12];
    #pragma unroll
    for (int p=0;p<12;++p) tr[p] = trans[fl*12+p];
    vn = (lane==10) ? 0.f : -10000.f;     // START=10
    float fa = fsh[fl];
    float fb = fsh[12+fl];
    for (int t=0;t<LSEQ;++t){
      unsigned vu = __float_as_uint(vn);
      float best; int bp; float sc;
      best = tr[0] + __uint_as_float(__builtin_amdgcn_readlane(vu,0)); bp = 0;
      sc = tr[1]  + __uint_as_float(__builtin_amdgcn_readlane(vu,1));  if(sc>best){best=sc;bp=1;}
      sc = tr[2]  + __uint_as_float(__builtin_amdgcn_readlane(vu,2));  if(sc>best){best=sc;bp=2;}
      sc = tr[3]  + __uint_as_float(__builtin_amdgcn_readlane(vu,3));  if(sc>best){best=sc;bp=3;}
      sc = tr[4]  + __uint_as_float(__builtin_amdgcn_readlane(vu,4));  if(sc>best){best=sc;bp=4;}
      sc = tr[5]  + __uint_as_float(__builtin_amdgcn_readlane(vu,5));  if(sc>best){best=sc;bp=5;}
      sc = tr[6]  + __uint_as_float(__builtin_amdgcn_readlane(vu,6));  if(sc>best){best=sc;bp=6;}
      sc = tr[7]  + __uint_as_float(__builtin_amdgcn_readlane(vu,7));  if(sc>best){best=sc;bp=7;}
      sc = tr[8]  + __uint_as_float(__builtin_amdgcn_readlane(vu,8));  if(sc>best){best=sc;bp=8;}
      sc = tr[9]  + __uint_as_float(__builtin_amdgcn_readlane(vu,9));  if(sc>best){best=sc;bp=9;}
      sc = tr[10] + __uint_as_float(__builtin_amdgcn_readlane(vu,10)); if(sc>best){best=sc;bp=10;}
      sc = tr[11] + __uint_as_float(__builtin_amdgcn_readlane(vu,11)); if(sc>best){best=sc;bp=11;}
      vn = best + fa;
      fa = fb;
      if (t+2 < LSEQ) fb = fsh[(t+2)*12+fl];
      if (lane<12) bps[t*12+lane] = (unsigned char)bp;
    }
  }
  if (tid < 12) term_sh[tid] = vn + trans[11*12+tid];   // STOP=11
  __syncthreads();
  if (tid == 0){
    float bs=term_sh[0]; int bt=0;
    for (int p=1;p<12;++p){ if (term_sh[p]>bs){bs=term_sh[p];bt=p;} }
    outp[0] = bs;
    ibuf[64] = bt;
  }
  __syncthreads();
  if (tid < 64){
    int b = tid;
    int f[12];
    int thi = b*32+31;
    #pragma unroll
    for (int x=0;x<12;++x) f[x] = bps[thi*12+x];
    for (int t=thi-1; t>=b*32; --t){
      int base = t*12;
      #pragma unroll
      for (int x=0;x<12;++x) f[x] = bps[base + f[x]];
    }
    #pragma unroll
    for (int x=0;x<12;++x) fmap[b*12+x] = (unsigned char)f[x];
  }
  __syncthreads();
  if (tid == 0){
    int tag = ibuf[64];
    for (int b=63;b>=0;--b){ ibuf[b]=tag; tag = fmap[b*12+tag]; }
  }
  __syncthreads();
  if (tid < 64){
    int b = tid;
    int tag = ibuf[b];
    for (int t=b*32+31; t>=b*32; --t){
      outp[1+t] = (float)tag;
      tag = bps[t*12+tag];
    }
  }
}

extern "C" void kernel_launch(void* const* d_in, const int* in_sizes, int n_in,
                              void* d_out, int out_size, void* d_ws, size_t ws_size,
                              hipStream_t stream) {
  const int*   sent   = (const int*)d_in[0];
  const float* embed  = (const float*)d_in[1];
  const float* w_ih_f = (const float*)d_in[2];
  const float* w_hh_f = (const float*)d_in[3];
  const float* b_ih_f = (const float*)d_in[4];
  const float* b_hh_f = (const float*)d_in[5];
  const float* w_ih_b = (const float*)d_in[6];
  const float* w_hh_b = (const float*)d_in[7];
  const float* b_ih_b = (const float*)d_in[8];
  const float* b_hh_b = (const float*)d_in[9];
  const float* w_out  = (const float*)d_in[10];
  const float* b_out  = (const float*)d_in[11];
  const float* trans  = (const float*)d_in[12];

  float* xg = (float*)d_ws;                                           // [2][L][1024] f32 = 16 MB
  unsigned short* hstH = (unsigned short*)(xg + (size_t)2*LSEQ*1024); // [2][L][256] f16 = 2 MB
  u64* ex = (u64*)(hstH + (size_t)2*LSEQ*256);  // slow 1024 + ring NSLOT*256 + rtab 32
  float* feats = (float*)(ex + 1024 + NSLOT*256 + NBLK);              // [L][12] f32 = 96 KB
  float* outp  = (float*)d_out;

  init_kernel<<<dim3((1024 + NSLOT*256 + NBLK + 255)/256), dim3(256), 0, stream>>>(ex);
  xg_kernel<<<dim3(LSEQ/8), dim3(256), 0, stream>>>(
      sent, embed, w_ih_f, b_ih_f, b_hh_f, w_ih_b, b_ih_b, b_hh_b, xg);
  lstm_rec<<<dim3(NBLK), dim3(256), 0, stream>>>(w_hh_f, w_hh_b, xg, hstH, ex);
  feats_kernel<<<dim3(LSEQ/16), dim3(256), 0, stream>>>(hstH, w_out, b_out, feats);
  BiLSTM_CRF_14405320311361_kernel<<<dim3(1), dim3(256), 0, stream>>>(feats, trans, outp);
}

// Round 7
// 3223.307 us; speedup vs baseline: 1.1475x; 1.0621x over previous
//
#include <hip/hip_runtime.h>

#define LSEQ 2048
#define TAGS 12
#define NSLOT 4     // exchange ring: tiny -> lines touched every step -> stay
                    // L2-resident -> sc0 publish is an L2 WRITE HIT (~200 cy),
                    // not an HBM write-allocate (~900 cy; round-6 FETCH +1.0MB
                    // proved the 128-slot ring was getting evicted by xg).
#define NBLK 32     // blocks launched for election (8 survive)

typedef _Float16 half2v __attribute__((ext_vector_type(2)));
typedef unsigned long long u64;

__device__ __forceinline__ float sigm(float x){ return 1.0f/(1.0f+__expf(-x)); }
__device__ __forceinline__ float tanh_fast(float x){ return 1.0f - 2.0f/(1.0f+__expf(2.0f*x)); }
__device__ __forceinline__ half2v pack2(float a, float b){
  half2v r; r.x=(_Float16)a; r.y=(_Float16)b; return r;
}

// Raw workgroup barrier: orders LDS only (lgkmcnt), does NOT drain vmcnt.
__device__ __forceinline__ void wg_barrier(){
  asm volatile("s_waitcnt lgkmcnt(0)" ::: "memory");
  __builtin_amdgcn_s_barrier();
  __builtin_amdgcn_sched_barrier(0);
  asm volatile("" ::: "memory");
}

// sc0 store: L1-write-through toward the issuing CU's XCD L2.
__device__ __forceinline__ void store_pub(u64* p, u64 v){
  asm volatile("global_store_dwordx2 %0, %1, off sc0"
               :: "v"(p), "v"(v) : "memory");
}

// K0: zero exchange buffers: slow parity (1024) + ring (NSLOT*256) + rtab (32).
__global__ void init_kernel(u64* ex)
{
  int tid = blockIdx.x*256 + threadIdx.x;
  if (tid < 1024 + NSLOT*256 + NBLK) ex[tid] = 0ull;
}

// K1: xg[d][t][row] = b_ih[row]+b_hh[row] + sum_e embed[sent[t]][e] * w_ih[row][e]
__global__ void xg_kernel(
    const int* sent, const float* embed,
    const float* w_ih_f, const float* b_ih_f, const float* b_hh_f,
    const float* w_ih_b, const float* b_ih_b, const float* b_hh_b,
    float* xg)
{
  __shared__ float x_sh[8][256];
  int tid = threadIdx.x;
  int t0 = blockIdx.x * 8;
  for (int i=0;i<8;++i){
    int idx = sent[t0+i];
    x_sh[i][tid] = embed[(size_t)idx*256 + tid];
  }
  __syncthreads();
  for (int ri=0; ri<8; ++ri){
    int r = ri*256 + tid;
    int d = r >> 10;
    int row = r & 1023;
    const float* wr = (d ? w_ih_b : w_ih_f) + (size_t)row*256;
    const float* bi = d ? b_ih_b : b_ih_f;
    const float* bh = d ? b_hh_b : b_hh_f;
    float acc[8];
    #pragma unroll
    for (int i=0;i<8;++i) acc[i]=0.f;
    for (int k0=0;k0<256;k0+=4){
      float4 p = *(const float4*)(wr + k0);
      #pragma unroll
      for (int i=0;i<8;++i){
        acc[i] += p.x*x_sh[i][k0] + p.y*x_sh[i][k0+1]
                + p.z*x_sh[i][k0+2] + p.w*x_sh[i][k0+3];
      }
    }
    float bias = bi[row] + bh[row];
    #pragma unroll
    for (int i=0;i<8;++i)
      xg[((size_t)d*LSEQ + (size_t)(t0+i))*1024 + row] = acc[i] + bias;
  }
}

// K2: bidirectional LSTM recurrence, 4 CUs/direction.
// Evidence chain (rounds 0-6):
//  r0-r2: barrier/schedule variants identical (2907~2910) -> exchange-bound.
//  r3: sc0-load spins at 246 cy (=L2 hit) never saw the tag -> %8 XCD bet
//      wrong -> runtime election added (r6).
//  r4: atomic probes found tags in ~1.2 spins, no speedup -> atomics pay
//      the ~1000 cy MALL RT regardless of sc bits.
//  r6: election + sc0 ring exchange: probe side fixed (L2 hit), but FETCH
//      +1.0 MB = publisher sc0 stores WRITE-ALLOCATING from HBM: the
//      128-slot ring (256 KB, 128-step reuse distance) was evicted by the
//      xg stream (~4 KB/step/CU) -> publish->visible stayed ~900 cy.
// This round: NSLOT=4 (8 KB ring, touched every step -> permanently MRU in
// the shared XCD L2). Publish = L2 write hit (~200 cy), probe = L2 read hit
// (~250 cy): the inter-CU chain finally runs at L2 latency.
// Tag safety at NSLOT=4: stale slot content is tag s-4 != s; writer of s+1
// coexisting with a reader of s-3 needs a peer 4 steps behind, but a
// publisher finishing step s implies all peers published tag s (finished
// step s-1) -> contradiction (same induction as the proven parity scheme).
// 8B aligned store can't tear. Slow-path fallback (atomicExch + agent-load
// spin after 512 fast spins, permanent demote) keeps it hang-proof.
__global__ __launch_bounds__(256,1) void lstm_rec(
    const float* __restrict__ w_hh_f, const float* __restrict__ w_hh_b,
    const float* __restrict__ xg, unsigned short* __restrict__ hstH,
    u64* __restrict__ ex)
{
  int blk = blockIdx.x;
  int tid = threadIdx.x;
  u64* rtab = ex + 1024 + NSLOT*256;   // [NBLK] election table

  __shared__ int role_sh[2];
  if (tid == 0){
    unsigned xcc;
    asm volatile("s_getreg_b32 %0, hwreg(HW_REG_XCC_ID)" : "=s"(xcc));
    xcc &= 15u;
    atomicExch(&rtab[blk], 0x100ull | (u64)xcc);   // bit8 = valid
    unsigned xs[NBLK];
    for (int i=0;i<NBLK;++i){
      u64 v;
      do {
        v = __hip_atomic_load(&rtab[i], __ATOMIC_RELAXED, __HIP_MEMORY_SCOPE_AGENT);
      } while (!(v & 0x100ull));
      xs[i] = (unsigned)v & 15u;
    }
    int dd = -1, qq = -1;
    unsigned taken = 0u;
    for (int dir = 0; dir < 2; ++dir){
      int pick = -1;
      for (int x = 0; x < 16 && pick < 0; ++x){
        int cnt = 0;
        for (int i=0;i<NBLK;++i)
          if (!((taken>>i)&1u) && xs[i]==(unsigned)x) ++cnt;
        if (cnt >= 4) pick = x;
      }
      int rank = 0;
      for (int i=0;i<NBLK && rank<4;++i){
        if (!((taken>>i)&1u) && pick >= 0 && xs[i]==(unsigned)pick){
          if (i == blk){ dd = dir; qq = rank; }
          taken |= 1u<<i; ++rank;
        }
      }
    }
    role_sh[0] = dd; role_sh[1] = qq;
  }
  __syncthreads();
  int d = role_sh[0];
  int q = role_sh[1];
  if (d < 0) return;                // 24 non-elected blocks exit

  int qa = (q+1)&3, qb = (q+2)&3, qc = (q+3)&3;
  int g = tid >> 6, l = tid & 63;
  int row = g*256 + 64*q + l;       // gate rows (PyTorch order i,f,g,o)
  const float* W = d ? w_hh_b : w_hh_f;
  const float* xgd = xg + (size_t)d*LSEQ*1024;
  unsigned short* hd = hstH + (size_t)d*LSEQ*256;
  u64* exS = ex + (size_t)d*256;              // slow: [2 parity][128 pairs]
  u64* exFd = ex + 1024 + (size_t)d*128;      // ring: [NSLOT][2 dir][128]

  __shared__ float gate_sh[2][256]; // parity-buffered [gate][64 units]
  __shared__ unsigned h2all[128];   // remote peers' packed f16 h-pairs

  // Permuted-column weights: w[0..31]=own pairs, then peers qa, qb, qc.
  half2v w[128];
  {
    const float* p0 = W + (size_t)row*256 + 64*q;
    const float* p1 = W + (size_t)row*256 + 64*qa;
    const float* p2 = W + (size_t)row*256 + 64*qb;
    const float* p3 = W + (size_t)row*256 + 64*qc;
    #pragma unroll
    for (int k0=0;k0<16;++k0){
      float4 a = *(const float4*)(p0+4*k0);
      w[2*k0]      = pack2(a.x,a.y);  w[2*k0+1]    = pack2(a.z,a.w);
      float4 b = *(const float4*)(p1+4*k0);
      w[32+2*k0]   = pack2(b.x,b.y);  w[32+2*k0+1] = pack2(b.z,b.w);
      float4 cc= *(const float4*)(p2+4*k0);
      w[64+2*k0]   = pack2(cc.x,cc.y); w[64+2*k0+1] = pack2(cc.z,cc.w);
      float4 e = *(const float4*)(p3+4*k0);
      w[96+2*k0]   = pack2(e.x,e.y);  w[96+2*k0+1] = pack2(e.z,e.w);
    }
  }
  if (tid < 128) h2all[tid] = 0u;
  float c0 = 0.f, c1 = 0.f;         // cell state: replicated, pair (l&31)
  unsigned hp = 0u;                 // own h-pair (l&31), replicated all lanes
  bool use_fast = true;             // per-thread demotion flag

  // loop-invariant addresses
  int pollj = tid - 64;                         // 0..95 for pollers
  int pollpeer = (q + 1 + (pollj>>5)) & 3;
  int pollslot = 32*pollpeer + (pollj & 31);    // valid when 64<=tid<160
  int adrA = (l < 32) ? (32*qa + l) : (32*qb + (l-32));
  int adrB = 32*qc + (l & 31);
  bool is_pub  = (tid < 32);                    // wave0 lanes 0-31: stores
  bool is_poll = (tid >= 64) && (tid < 160);    // waves 1-2: polls
  __syncthreads();

  int tf = d ? (LSEQ-1) : 0;
  float xg0 = xgd[(size_t)tf*1024 + row];

  for (int s=0;s<LSEQ;++s){
    bool p = is_poll && (s > 0);
    // --- probe issue BEFORE local dot: its L2 RT hides under the dot.
    u64 pv_ = 0ull;
    u64* fp = &exFd[(((unsigned)s & (NSLOT-1))<<8) + pollslot];
    if (p && use_fast){
      asm volatile("global_load_dwordx2 %0, %1, off sc0"
                   : "+v"(pv_) : "v"(fp) : "memory");
    }
    // --- xg prefetch: issued UNCONDITIONALLY (clamped addr at the last
    //     step) so the probe's vmcnt(1) check below always has exactly the
    //     xg load as the younger outstanding op.  (r6 had a latent race at
    //     s==LSEQ-1 where vmcnt(1) could read the probe mid-flight.)
    int tn = (s+1 < LSEQ) ? (d ? (LSEQ-2-s) : (s+1)) : tf;
    float nxg = xgd[(size_t)tn*1024 + row];
    // --- local quarter dot: own 32 h-pairs straight from registers
    float a0=xg0, a1=0.f, a2=0.f, a3=0.f;
    #pragma unroll
    for (int k=0;k<32;k+=4){
      unsigned p0v = __builtin_amdgcn_readlane(hp,k);
      unsigned p1v = __builtin_amdgcn_readlane(hp,k+1);
      unsigned p2v = __builtin_amdgcn_readlane(hp,k+2);
      unsigned p3v = __builtin_amdgcn_readlane(hp,k+3);
      a0 = __builtin_amdgcn_fdot2(__builtin_bit_cast(half2v,p0v), w[k],   a0, false);
      a1 = __builtin_amdgcn_fdot2(__builtin_bit_cast(half2v,p1v), w[k+1], a1, false);
      a2 = __builtin_amdgcn_fdot2(__builtin_bit_cast(half2v,p2v), w[k+2], a2, false);
      a3 = __builtin_amdgcn_fdot2(__builtin_bit_cast(half2v,p3v), w[k+3], a3, false);
    }
    // --- poll check: counted wait (xg load is the 1 younger outstanding op),
    //     short sc0 re-probe spin, then permanent demote to slow path.
    if (p){
      u64 v = 0ull;
      if (use_fast){
        asm volatile("s_waitcnt vmcnt(1)" : "+v"(pv_) :: "memory");
        v = pv_;
        int spins = 0;
        while ((unsigned)(v>>32) != (unsigned)s && spins < 512){
          asm volatile("global_load_dwordx2 %0, %1, off sc0\n\t"
                       "s_waitcnt vmcnt(0)"
                       : "+v"(v) : "v"(fp) : "memory");
          ++spins;
        }
        if ((unsigned)(v>>32) != (unsigned)s) use_fast = false;
      }
      if (!use_fast){
        while ((unsigned)(v>>32) != (unsigned)s)
          v = __hip_atomic_load(&exS[((s&1)<<7) + pollslot],
                                __ATOMIC_RELAXED, __HIP_MEMORY_SCOPE_AGENT);
      }
      h2all[pollslot] = (unsigned)v;
    }
    wg_barrier();                    // #1: pollers' LDS writes -> all waves
    // --- remote 3/4 dot: hrA lanes 0-31 = peer qa pairs, 32-63 = peer qb;
    //     hrB lanes 0-31 = peer qc pairs. All readlane/reg indices static.
    unsigned hrA = h2all[adrA];
    unsigned hrB = h2all[adrB];
    #pragma unroll
    for (int k=0;k<32;k+=2){
      unsigned pA0 = __builtin_amdgcn_readlane(hrA, k);
      unsigned pA1 = __builtin_amdgcn_readlane(hrA, k+1);
      unsigned pB0 = __builtin_amdgcn_readlane(hrA, 32+k);
      unsigned pB1 = __builtin_amdgcn_readlane(hrA, 32+k+1);
      unsigned pC0 = __builtin_amdgcn_readlane(hrB, k);
      unsigned pC1 = __builtin_amdgcn_readlane(hrB, k+1);
      a0 = __builtin_amdgcn_fdot2(__builtin_bit_cast(half2v,pA0), w[32+k],   a0, false);
      a1 = __builtin_amdgcn_fdot2(__builtin_bit_cast(half2v,pA1), w[32+k+1], a1, false);
      a2 = __builtin_amdgcn_fdot2(__builtin_bit_cast(half2v,pB0), w[64+k],   a2, false);
      a3 = __builtin_amdgcn_fdot2(__builtin_bit_cast(half2v,pB1), w[64+k+1], a3, false);
      a0 = __builtin_amdgcn_fdot2(__builtin_bit_cast(half2v,pC0), w[96+k],   a0, false);
      a1 = __builtin_amdgcn_fdot2(__builtin_bit_cast(half2v,pC1), w[96+k+1], a1, false);
    }
    float pre = (a0+a1) + (a2+a3);
    float act = (g==2) ? tanh_fast(pre) : sigm(pre);
    gate_sh[s&1][tid] = act;         // [g][64]: tid = g*64 + l
    wg_barrier();                    // #2: gate writes -> update reads
    // --- update, replicated on ALL lanes (deterministic -> identical hp)
    {
      int m = l & 31;
      const float* gp = gate_sh[s&1];
      float2 gi = *(const float2*)&gp[      2*m];
      float2 gf = *(const float2*)&gp[ 64 + 2*m];
      float2 gg = *(const float2*)&gp[128 + 2*m];
      float2 go = *(const float2*)&gp[192 + 2*m];
      c0 = gf.x*c0 + gi.x*gg.x;
      c1 = gf.y*c1 + gi.y*gg.y;
      float h0 = go.x * tanh_fast(c0);
      float h1 = go.y * tanh_fast(c1);
      hp = __builtin_bit_cast(unsigned, pack2(h0,h1));
    }
    // --- wave0: publish h(s) tagged s+1: ring sc0 store (hot L2 line) +
    //     coherent atomicExch fallback; plus h history. Fire-and-forget.
    if (is_pub){
      if (s+1 < LSEQ){
        u64 pv = ((u64)(unsigned)(s+1) << 32) | (u64)hp;
        store_pub(&exFd[(((unsigned)(s+1) & (NSLOT-1))<<8) + 32*q + tid], pv);
        atomicExch(&exS[(((s+1)&1)<<7) + 32*q + tid], pv);
      }
      int tp = d ? (LSEQ-1-s) : s;
      *(unsigned*)&hd[(size_t)tp*256 + 64*q + 2*tid] = hp;
    }
    xg0 = nxg;
    // no barrier #3: gate_sh is parity-buffered; h2all reads(s) and poller
    // writes(s+1) are separated by barrier #2(s); hp/c are registers.
  }
}

// K3: feats[t][tag] = b_out[tag] + [hf|hb] . w_out[tag]   (h history is f16)
__global__ void feats_kernel(
    const unsigned short* hstH, const float* w_out, const float* b_out,
    float* feats)
{
  __shared__ float w_sh[12*520];
  __shared__ float h_sh[16*520];
  const _Float16* hf = (const _Float16*)hstH;
  int tid=threadIdx.x;
  int t0=blockIdx.x*16;
  for (int i=tid;i<12*512;i+=256){ int tag=i>>9,k=i&511; w_sh[tag*520+k]=w_out[i]; }
  for (int i=tid;i<16*512;i+=256){
    int tt=i>>9,k=i&511;
    float v = (k<256)? (float)hf[(size_t)(t0+tt)*256+k]
                     : (float)hf[(size_t)(LSEQ+t0+tt)*256 + (k-256)];
    h_sh[tt*520+k]=v;
  }
  __syncthreads();
  if (tid<192){
    int tt=tid/12, tag=tid%12;
    const float* wr=&w_sh[tag*520];
    const float* hr=&h_sh[tt*520];
    float acc=b_out[tag];
    for (int k=0;k<512;k+=4){
      float4 a=*(const float4*)(wr+k);
      float4 b=*(const float4*)(hr+k);
      acc += a.x*b.x+a.y*b.y+a.z*b.z+a.w*b.w;
    }
    feats[(size_t)(t0+tt)*12+tag]=acc;
  }
}

// K4: Viterbi DP: feats in LDS, v register-resident via readlane; parallel
// block-composed backtrack.
__global__ void BiLSTM_CRF_14405320311361_kernel(
    const float* feats, const float* trans, float* outp)
{
  __shared__ float fsh[LSEQ*12];           // 96 KB
  __shared__ unsigned char bps[LSEQ*12];   // 24 KB
  __shared__ float term_sh[16];
  __shared__ int ibuf[66];
  __shared__ unsigned char fmap[64*12];
  int tid = threadIdx.x;
  for (int i=tid; i<LSEQ*12/4; i+=256)
    *(float4*)&fsh[4*i] = *(const float4*)&feats[4*i];
  __syncthreads();

  int lane = tid & 63;
  int fl = (lane<12) ? lane : 0;
  float vn = 0.f;
  if (tid < 64){
    float tr[12];
    #pragma unroll
    for (int p=0;p<12;++p) tr[p] = trans[fl*12+p];
    vn = (lane==10) ? 0.f : -10000.f;     // START=10
    float fa = fsh[fl];
    float fb = fsh[12+fl];
    for (int t=0;t<LSEQ;++t){
      unsigned vu = __float_as_uint(vn);
      float best; int bp; float sc;
      best = tr[0] + __uint_as_float(__builtin_amdgcn_readlane(vu,0)); bp = 0;
      sc = tr[1]  + __uint_as_float(__builtin_amdgcn_readlane(vu,1));  if(sc>best){best=sc;bp=1;}
      sc = tr[2]  + __uint_as_float(__builtin_amdgcn_readlane(vu,2));  if(sc>best){best=sc;bp=2;}
      sc = tr[3]  + __uint_as_float(__builtin_amdgcn_readlane(vu,3));  if(sc>best){best=sc;bp=3;}
      sc = tr[4]  + __uint_as_float(__builtin_amdgcn_readlane(vu,4));  if(sc>best){best=sc;bp=4;}
      sc = tr[5]  + __uint_as_float(__builtin_amdgcn_readlane(vu,5));  if(sc>best){best=sc;bp=5;}
      sc = tr[6]  + __uint_as_float(__builtin_amdgcn_readlane(vu,6));  if(sc>best){best=sc;bp=6;}
      sc = tr[7]  + __uint_as_float(__builtin_amdgcn_readlane(vu,7));  if(sc>best){best=sc;bp=7;}
      sc = tr[8]  + __uint_as_float(__builtin_amdgcn_readlane(vu,8));  if(sc>best){best=sc;bp=8;}
      sc = tr[9]  + __uint_as_float(__builtin_amdgcn_readlane(vu,9));  if(sc>best){best=sc;bp=9;}
      sc = tr[10] + __uint_as_float(__builtin_amdgcn_readlane(vu,10)); if(sc>best){best=sc;bp=10;}
      sc = tr[11] + __uint_as_float(__builtin_amdgcn_readlane(vu,11)); if(sc>best){best=sc;bp=11;}
      vn = best + fa;
      fa = fb;
      if (t+2 < LSEQ) fb = fsh[(t+2)*12+fl];
      if (lane<12) bps[t*12+lane] = (unsigned char)bp;
    }
  }
  if (tid < 12) term_sh[tid] = vn + trans[11*12+tid];   // STOP=11
  __syncthreads();
  if (tid == 0){
    float bs=term_sh[0]; int bt=0;
    for (int p=1;p<12;++p){ if (term_sh[p]>bs){bs=term_sh[p];bt=p;} }
    outp[0] = bs;
    ibuf[64] = bt;
  }
  __syncthreads();
  if (tid < 64){
    int b = tid;
    int f[12];
    int thi = b*32+31;
    #pragma unroll
    for (int x=0;x<12;++x) f[x] = bps[thi*12+x];
    for (int t=thi-1; t>=b*32; --t){
      int base = t*12;
      #pragma unroll
      for (int x=0;x<12;++x) f[x] = bps[base + f[x]];
    }
    #pragma unroll
    for (int x=0;x<12;++x) fmap[b*12+x] = (unsigned char)f[x];
  }
  __syncthreads();
  if (tid == 0){
    int tag = ibuf[64];
    for (int b=63;b>=0;--b){ ibuf[b]=tag; tag = fmap[b*12+tag]; }
  }
  __syncthreads();
  if (tid < 64){
    int b = tid;
    int tag = ibuf[b];
    for (int t=b*32+31; t>=b*32; --t){
      outp[1+t] = (float)tag;
      tag = bps[t*12+tag];
    }
  }
}

extern "C" void kernel_launch(void* const* d_in, const int* in_sizes, int n_in,
                              void* d_out, int out_size, void* d_ws, size_t ws_size,
                              hipStream_t stream) {
  const int*   sent   = (const int*)d_in[0];
  const float* embed  = (const float*)d_in[1];
  const float* w_ih_f = (const float*)d_in[2];
  const float* w_hh_f = (const float*)d_in[3];
  const float* b_ih_f = (const float*)d_in[4];
  const float* b_hh_f = (const float*)d_in[5];
  const float* w_ih_b = (const float*)d_in[6];
  const float* w_hh_b = (const float*)d_in[7];
  const float* b_ih_b = (const float*)d_in[8];
  const float* b_hh_b = (const float*)d_in[9];
  const float* w_out  = (const float*)d_in[10];
  const float* b_out  = (const float*)d_in[11];
  const float* trans  = (const float*)d_in[12];

  float* xg = (float*)d_ws;                                           // [2][L][1024] f32 = 16 MB
  unsigned short* hstH = (unsigned short*)(xg + (size_t)2*LSEQ*1024); // [2][L][256] f16 = 2 MB
  u64* ex = (u64*)(hstH + (size_t)2*LSEQ*256);  // slow 1024 + ring NSLOT*256 + rtab 32
  float* feats = (float*)(ex + 1024 + NSLOT*256 + NBLK);              // [L][12] f32 = 96 KB
  float* outp  = (float*)d_out;

  init_kernel<<<dim3((1024 + NSLOT*256 + NBLK + 255)/256), dim3(256), 0, stream>>>(ex);
  xg_kernel<<<dim3(LSEQ/8), dim3(256), 0, stream>>>(
      sent, embed, w_ih_f, b_ih_f, b_hh_f, w_ih_b, b_ih_b, b_hh_b, xg);
  lstm_rec<<<dim3(NBLK), dim3(256), 0, stream>>>(w_hh_f, w_hh_b, xg, hstH, ex);
  feats_kernel<<<dim3(LSEQ/16), dim3(256), 0, stream>>>(hstH, w_out, b_out, feats);
  BiLSTM_CRF_14405320311361_kernel<<<dim3(1), dim3(256), 0, stream>>>(feats, trans, outp);
}